// Round 4
// baseline (340.415 us; speedup 1.0000x reference)
//
#include <hip/hip_runtime.h>
#include <hip/hip_bf16.h>

using s8v   = __attribute__((ext_vector_type(8))) short;
using f32x4 = __attribute__((ext_vector_type(4))) float;

#define N_TOT 100352              // 32*56*56
#define WT_ELEMS 589824           // 2 mt * 72 ksteps * 128 rows * 4 slots * 8 shorts
#define PLANE_ELEMS 861184        // 32*58*58*8 (one channel-group plane)
#define XT_ELEMS 27557888         // 32 planes
#define WS_NEED  56295424         // bytes: 2*(WT_ELEMS+XT_ELEMS)

#define BAR() __builtin_amdgcn_s_barrier()

__device__ __forceinline__ unsigned short f2bf(float f) {
    unsigned int u = __float_as_uint(f);
    unsigned int r = (u + 0x7FFF + ((u >> 16) & 1)) >> 16;  // RNE
    return (unsigned short)r;
}

__device__ __forceinline__ void gl_lds16(const void* g, void* l) {
    __builtin_amdgcn_global_load_lds(
        (const __attribute__((address_space(1))) unsigned int*)g,
        (__attribute__((address_space(3))) unsigned int*)l, 16, 0, 0);
}

// weights [O=256][C=256][9] fp32 -> wt: [mt 2][kstep 72][o 128][slot 4] 16B units.
// kstep = cb*9+tap (BK=32 = 32 channels of one tap). XOR-pre-swizzled: slot s of
// row o holds chunk c = s ^ ((o>>1)&3) = channels cb*32 + c*8 .. +8.
// gemm A-stage is then a pure linear copy; swizzled ds_read is <=2-way (free).
__global__ void prep_w(const float* __restrict__ w, unsigned short* __restrict__ wt) {
    int u  = blockIdx.x * 256 + threadIdx.x;  // 0..73727 16B-units
    int s  = u & 3;
    int o  = (u >> 2) & 127;
    int kt = u >> 9;                          // mt*72 + ks
    int mt = kt / 72;
    int ks = kt - mt * 72;
    int cb = ks / 9, tap = ks - cb * 9;
    int c  = s ^ ((o >> 1) & 3);
    int og = mt * 128 + o;
    int c0 = cb * 32 + c * 8;
    const float* src = w + ((size_t)(og * 256 + c0)) * 9 + tap;
    unsigned int p[4];
    #pragma unroll
    for (int q = 0; q < 4; ++q) {
        float f0 = src[(2 * q) * 9];
        float f1 = src[(2 * q + 1) * 9];
        p[q] = (unsigned)f2bf(f0) | ((unsigned)f2bf(f1) << 16);
    }
    *(uint4*)(wt + (size_t)u * 8) = *(uint4*)p;
}

// x [32][256][56][56] fp32 -> Xt [cg=32][b=32][hp=58][wp=58][8ch] bf16, zero-padded.
__global__ void prep_x(const float* __restrict__ x, unsigned short* __restrict__ xt) {
    int b  = blockIdx.x / 58;
    int hp = blockIdx.x % 58;
    int tid = threadIdx.x;
    uint4 zero = {0u, 0u, 0u, 0u};
    size_t rowbase = (size_t)(b * 58 + hp) * 58;
    if (hp == 0 || hp == 57) {
        for (int i = tid; i < 1856; i += 256) {
            int cg = i / 58, wp = i - cg * 58;
            *(uint4*)(xt + ((size_t)cg * PLANE_ELEMS + (rowbase + wp) * 8)) = zero;
        }
        return;
    }
    int h = hp - 1;
    int wave = tid >> 6, lane = tid & 63;
    for (int cg = wave; cg < 32; cg += 4) {
        unsigned short* outp = xt + (size_t)cg * PLANE_ELEMS + rowbase * 8;
        if (lane < 56) {
            const float* src = x + ((size_t)(b * 256 + cg * 8) * 3136 + h * 56 + lane);
            unsigned int p[4];
            #pragma unroll
            for (int q = 0; q < 4; ++q) {
                float f0 = src[(size_t)(2 * q) * 3136];
                float f1 = src[(size_t)(2 * q + 1) * 3136];
                p[q] = (unsigned)f2bf(f0) | ((unsigned)f2bf(f1) << 16);
            }
            *(uint4*)(outp + (size_t)(lane + 1) * 8) = *(uint4*)p;
        } else if (lane == 56) {
            *(uint4*)outp = zero;
        } else if (lane == 57) {
            *(uint4*)(outp + 57 * 8) = zero;
        }
    }
}

// Implicit-GEMM conv, occupancy-first: 128(BM-half... mt picks 128 of 256 O)x128 tile,
// BK=32, 256 threads (4 waves 2m x 2n, wave-tile 64x64), 32 KiB LDS static ->
// 4 blocks/CU (16 waves/CU). Classic 2-deep prefetch, one vmcnt(4) + 2 raw barriers
// per kstep; cross-block TLP hides barrier/LDS/MFMA serialization (m114).
// LDS rows are 64B (4x16B slots), XOR-swizzled slot^=(row>>1)&3 -> <=2-way reads.
__global__ __launch_bounds__(256, 4) void gemm4(const unsigned short* __restrict__ wt,
                                                const unsigned short* __restrict__ xt,
                                                float* __restrict__ out) {
    __shared__ char lds[32768];               // [buf 2][A 8192 | B 8192]
    int bx  = blockIdx.x;
    int swz = (bx & 7) * 196 + (bx >> 3);     // 1568 = 8*196: bijective XCD swizzle
    int mt  = swz >= 784;                     // XCDs 0-3 -> mt0, 4-7 -> mt1 (A L2-reuse)
    int nt  = swz - mt * 784;
    int tid = threadIdx.x;
    int w   = tid >> 6, lane = tid & 63;
    int l16 = lane & 15, quad = lane >> 4;
    int wm  = w >> 1,  wn = w & 1;

    const char* xtB = (const char*)xt;
    const char* aT  = (const char*)wt + (size_t)mt * 72 * 8192;

    // ---- staging constants
    int sA0 = (w * 2) * 1024, sA1 = sA0 + 1024;   // uniform slot bases (src & dst)
    int laneB = lane * 16;
    // B gather: lane l supplies unit (pix = slot*16 + (l>>2), s = l&3) holding
    // chunk c = s ^ ((pix>>1)&3) = (l&3) ^ ((l>>3)&3)  (lane-constant)
    int cPo = (((lane & 3) ^ ((lane >> 3) & 3)) * PLANE_ELEMS) * 2;  // bytes
    int bpo[2];
    #pragma unroll
    for (int it = 0; it < 2; ++it) {
        int p = (w * 2 + it) * 16 + (lane >> 2);
        int n = nt * 128 + p;
        int b = n / 3136; int rr = n - b * 3136;
        int h = rr / 56;  int wc = rr - h * 56;
        bpo[it] = cPo + (((b * 58 + h) * 58 + wc) * 8) * 2;   // bytes, pad-origin
    }
    int bpo0 = bpo[0], bpo1 = bpo[1];

    // ---- ds_read bases: row*64 + (chunk ^ ((row>>1)&3))*16, chunk = quad
    int swzr = (quad ^ ((l16 >> 1) & 3)) << 4;
    int aRd = (wm * 64 + l16) * 64 + swzr;
    int bRd = 8192 + (wn * 64 + l16) * 64 + swzr;

    f32x4 acc[4][4] = {};

    // ---- prologue: stage kstep 0 -> buf0
    {
        char* A = lds; char* B = lds + 8192;
        gl_lds16(aT + sA0 + laneB, A + sA0);
        gl_lds16(aT + sA1 + laneB, A + sA1);
        gl_lds16(xtB + bpo0, B + sA0);
        gl_lds16(xtB + bpo1, B + sA1);
    }

    const char* aTn = aT + 8192;
    int dwN = 1, dhN = 0, cbN = 0;            // counters for NEXT kstep (=1)
    int boN = 16;                             // bytes: cb*4*PLANE*2 + ts*16

    #pragma unroll 1
    for (int t = 0; t < 71; ++t) {
        // stage kstep t+1 into buf (t+1)&1 (its old tile was read in iter t-1)
        char* A = lds + ((t + 1) & 1) * 16384;
        char* B = A + 8192;
        gl_lds16(aTn + sA0 + laneB, A + sA0);
        gl_lds16(aTn + sA1 + laneB, A + sA1);
        gl_lds16(xtB + boN + bpo0, B + sA0);
        gl_lds16(xtB + boN + bpo1, B + sA1);
        aTn += 8192;
        if (++dwN == 3) { dwN = 0; if (++dhN == 3) { dhN = 0; ++cbN; } }
        boN = cbN * (4 * PLANE_ELEMS * 2) + (dhN * 58 + dwN) * 16;

        asm volatile("s_waitcnt vmcnt(4)" ::: "memory");   // kstep t landed
        BAR();
        const char* base = lds + (t & 1) * 16384;
        s8v af[4], bf[4];
        #pragma unroll
        for (int f = 0; f < 4; ++f) af[f] = *(const s8v*)(base + aRd + f * 1024);
        #pragma unroll
        for (int g = 0; g < 4; ++g) bf[g] = *(const s8v*)(base + bRd + g * 1024);
        __builtin_amdgcn_s_setprio(1);
        #pragma unroll
        for (int f = 0; f < 4; ++f)
            #pragma unroll
            for (int g = 0; g < 4; ++g)
                acc[f][g] = __builtin_amdgcn_mfma_f32_16x16x32_bf16(af[f], bf[g], acc[f][g], 0, 0, 0);
        __builtin_amdgcn_s_setprio(0);
        BAR();
    }
    // ---- t = 71: no stage, full drain
    {
        asm volatile("s_waitcnt vmcnt(0)" ::: "memory");
        BAR();
        const char* base = lds + 16384;       // buf1
        s8v af[4], bf[4];
        #pragma unroll
        for (int f = 0; f < 4; ++f) af[f] = *(const s8v*)(base + aRd + f * 1024);
        #pragma unroll
        for (int g = 0; g < 4; ++g) bf[g] = *(const s8v*)(base + bRd + g * 1024);
        #pragma unroll
        for (int f = 0; f < 4; ++f)
            #pragma unroll
            for (int g = 0; g < 4; ++g)
                acc[f][g] = __builtin_amdgcn_mfma_f32_16x16x32_bf16(af[f], bf[g], acc[f][g], 0, 0, 0);
    }

    // ---- epilogue: C/D col=l16 (n), row=quad*4+reg (m=o). out is [O][N_TOT].
    float* op = out + (size_t)(mt * 128 + wm * 64 + quad * 4) * N_TOT + nt * 128 + wn * 64 + l16;
    #pragma unroll
    for (int f = 0; f < 4; ++f)
        #pragma unroll
        for (int rr = 0; rr < 4; ++rr) {
            float* orow = op + (size_t)(f * 16 + rr) * N_TOT;
            #pragma unroll
            for (int g = 0; g < 4; ++g)
                orow[g * 16] = acc[f][g][rr];
        }
}

// Fallback if workspace too small: direct conv, one thread per output.
__global__ void conv_naive(const float* __restrict__ x, const float* __restrict__ wq,
                           float* __restrict__ out) {
    int f = blockIdx.x * 256 + threadIdx.x;
    int o = f / N_TOT;
    int n = f - o * N_TOT;
    int b = n / 3136; int r = n - b * 3136; int h = r / 56; int w = r - h * 56;
    const float* xb = x + (size_t)b * 256 * 3136;
    const float* wo = wq + o * 2304;
    float acc = 0.f;
    for (int c = 0; c < 256; ++c) {
        const float* xc = xb + c * 3136;
        const float* wc = wo + c * 9;
        #pragma unroll
        for (int dh = 0; dh < 3; ++dh) {
            int ih = h + dh - 1;
            if (ih < 0 || ih >= 56) continue;
            const float* xr = xc + ih * 56;
            #pragma unroll
            for (int dw = 0; dw < 3; ++dw) {
                int iw = w + dw - 1;
                if (iw >= 0 && iw < 56) acc += xr[iw] * wc[dh * 3 + dw];
            }
        }
    }
    out[f] = acc;
}

extern "C" void kernel_launch(void* const* d_in, const int* in_sizes, int n_in,
                              void* d_out, int out_size, void* d_ws, size_t ws_size,
                              hipStream_t stream) {
    const float* x = (const float*)d_in[0];
    const float* w = (const float*)d_in[1];
    float* out = (float*)d_out;
    if (ws_size >= (size_t)WS_NEED) {
        unsigned short* wt = (unsigned short*)d_ws;
        unsigned short* xt = wt + WT_ELEMS;
        prep_w<<<288, 256, 0, stream>>>(w, wt);
        prep_x<<<32 * 58, 256, 0, stream>>>(x, xt);
        gemm4<<<1568, 256, 0, stream>>>(wt, xt, out);
    } else {
        conv_naive<<<N_TOT, 256, 0, stream>>>(x, w, out);
    }
}

// Round 5
// 318.965 us; speedup vs baseline: 1.0672x; 1.0672x over previous
//
#include <hip/hip_runtime.h>
#include <hip/hip_bf16.h>

using s8v   = __attribute__((ext_vector_type(8))) short;
using f32x4 = __attribute__((ext_vector_type(4))) float;

#define N_TOT 100352              // 32*56*56
#define WT_ELEMS 589824           // 36 K-tiles * 2048 units * 8 shorts
#define XT_ELEMS 27557888         // 32*58*58 pixels * 256 ch (pixel-major, 512B/pixel)
#define WS_NEED  56295424         // bytes: 2*(WT_ELEMS+XT_ELEMS)

#define BAR() asm volatile("s_barrier" ::: "memory")
#define GATE(T) do { if ((T) < 33) asm volatile("s_waitcnt vmcnt(8)" ::: "memory"); \
                     else          asm volatile("s_waitcnt vmcnt(0)" ::: "memory"); } while (0)

__device__ __forceinline__ unsigned short f2bf(float f) {
    unsigned int u = __float_as_uint(f);
    unsigned int r = (u + 0x7FFF + ((u >> 16) & 1)) >> 16;  // RNE
    return (unsigned short)r;
}

__device__ __forceinline__ void gl_lds16(const void* g, void* l) {
    __builtin_amdgcn_global_load_lds(
        (const __attribute__((address_space(1))) unsigned int*)g,
        (__attribute__((address_space(3))) unsigned int*)l, 16, 0, 0);
}

// weights [O=256][C=256][9] fp32 -> wt: 36 K-tiles (BK=64 = ksteps 2t,2t+1)
// Tile = exact LDS image [row o=0..255][slot s=0..7] of 16B units, XOR-pre-swizzled:
// slot s of row o holds k-chunk ksub = s ^ (o&7); ksub=(ks<<2)|c2 -> kstep 2t+ks,
// channels cb*32 + c2*8 .. +8. gemm A-stage is a pure linear copy.
__global__ void prep_w(const float* __restrict__ w, unsigned short* __restrict__ wt) {
    int u = blockIdx.x * 256 + threadIdx.x;   // 0..73727 16B-units
    int kt = u >> 11;
    int r  = u & 2047;
    int o  = r >> 3;
    int s  = r & 7;
    int ksub  = s ^ (o & 7);
    int kstep = kt * 2 + (ksub >> 2);
    int cb = kstep / 9, tap = kstep - cb * 9;
    int c0 = cb * 32 + (ksub & 3) * 8;
    const float* src = w + ((size_t)(o * 256 + c0)) * 9 + tap;
    unsigned int p[4];
    #pragma unroll
    for (int q = 0; q < 4; ++q) {
        float f0 = src[(2 * q) * 9];
        float f1 = src[(2 * q + 1) * 9];
        p[q] = (unsigned)f2bf(f0) | ((unsigned)f2bf(f1) << 16);
    }
    *(uint4*)(wt + (size_t)u * 8) = *(uint4*)p;
}

// x [32][256][56][56] fp32 -> xt [b 32][hp 58][wp 58][c 256] bf16, zero-padded.
// PIXEL-MAJOR: all 256 channels contiguous per pixel (512 B) so the gemm's B-gather
// is 64B-window coalesced. LDS transpose: [c][w] -> [w][c], 4 passes of 64 channels.
__global__ void prep_x(const float* __restrict__ x, unsigned short* __restrict__ xt) {
    int b  = blockIdx.x / 58;
    int hp = blockIdx.x % 58;
    int tid = threadIdx.x;
    uint4 zero = {0u, 0u, 0u, 0u};
    size_t rowbase = (size_t)(b * 58 + hp) * 58 * 256;   // ushort idx of (wp=0, c=0)
    if (hp == 0 || hp == 57) {
        for (int i = tid; i < 1856; i += 256)            // 58*512B = 1856 uint4
            *(uint4*)(xt + rowbase + (size_t)i * 8) = zero;
        return;
    }
    int h = hp - 1;
    __shared__ unsigned short T[56][72];                 // stride 144B: 16B-aligned rows
    int wv = tid >> 6, lane = tid & 63;
    int p   = tid >> 2, seg = tid & 3;
    #pragma unroll 1
    for (int pass = 0; pass < 4; ++pass) {
        // read: wave wv covers channels pass*64 + wv*16 .. +15; lanes = w (coalesced)
        #pragma unroll
        for (int j = 0; j < 16; ++j) {
            int c = pass * 64 + wv * 16 + j;
            if (lane < 56)
                T[lane][wv * 16 + j] = f2bf(x[((size_t)(b * 256 + c)) * 3136 + h * 56 + lane]);
        }
        __syncthreads();
        // write: thread t -> pixel p, 16 channels seg*16.. (32B contiguous global)
        if (p < 56) {
            unsigned short* dst = xt + rowbase + (size_t)(p + 1) * 256 + pass * 64 + seg * 16;
            *(uint4*)dst       = *(uint4*)&T[p][seg * 16];
            *(uint4*)(dst + 8) = *(uint4*)&T[p][seg * 16 + 8];
        }
        __syncthreads();
    }
    // in-row pads: wp=0 and wp=57 (512 B each)
    if (tid < 32)       *(uint4*)(xt + rowbase + (size_t)tid * 8) = zero;
    else if (tid < 64)  *(uint4*)(xt + rowbase + (size_t)57 * 256 + (size_t)(tid - 32) * 8) = zero;
}

// 256x256xBK64 implicit-GEMM conv. ONE barrier per phase; each phase:
//   { BAR; ds_read NEXT consumer's frags; stage 1 half-tile; MFMA on regs read
//     a phase earlier; vmcnt(8) }
// Identical to round-3 structure; only the B-gather addressing changed to the
// pixel-major xt (consecutive lanes -> contiguous 64B windows, TA-coalescable).
__global__ __launch_bounds__(512, 2) void gemm8(const unsigned short* __restrict__ wt,
                                                const unsigned short* __restrict__ xt,
                                                float* __restrict__ out) {
    extern __shared__ char lds[];             // 131072 B: [buf 2][A 32768 | B 32768]
    int bx = blockIdx.x;
    int nt = (bx & 7) * 49 + (bx >> 3);       // 392 = 8*49: bijective XCD swizzle
    int tid  = threadIdx.x;
    int w    = tid >> 6, lane = tid & 63;
    int l16  = lane & 15, quad = lane >> 4;
    int wm   = w >> 2,   wn   = w & 3;
    int lane16 = lane * 16;

    // ---- staging constants. slots s = w*2+it (it=0,1), 16 slots x 8 rows/pixels.
    int s0 = w * 2, s1 = w * 2 + 1;
    int adst0 = ((s0 >> 3) * 128 + (s0 & 7) * 8) * 128;
    int adst1 = ((s1 >> 3) * 128 + (s1 & 7) * 8) * 128;
    int bp0 = ((s0 >> 2) * 64 + (s0 & 3) * 8);
    int bp1 = ((s1 >> 2) * 64 + (s1 & 3) * 8);
    int bdst0 = bp0 * 128;
    int bdst1 = bp1 * 128;
    // per-lane k-chunk for B gather: lane l supplies slot l&7 of pixel base+(l>>3),
    // holding ksub = (l&7)^((l>>3)&7); ksub=(ks<<2)|c2 -> byte off c2*16 within pixel
    int ksub  = (lane & 7) ^ (lane >> 3);
    int ksl   = ksub >> 2;
    int c2off = (ksub & 3) * 16;              // bytes within the 32-ch block
    // pad-origin pixel BYTE offsets for the 4 (it,h) staging targets
    int pix[2][2];
    #pragma unroll
    for (int it = 0; it < 2; ++it)
        #pragma unroll
        for (int h = 0; h < 2; ++h) {
            int n = nt * 256 + (it ? bp1 : bp0) + h * 32 + (lane >> 3);
            int b = n / 3136; int rr = n - b * 3136;
            int hh = rr / 56; int ww = rr - hh * 56;
            pix[it][h] = ((b * 58 + hh) * 58 + ww) * 512;
        }
    int pix00 = pix[0][0], pix01 = pix[0][1], pix10 = pix[1][0], pix11 = pix[1][1];

    // ---- ds_read per-lane bases: row*128 + (chunk ^ (row&7))*16, chunk = ks*4+quad
    int swz = (quad ^ (l16 & 7)) << 4;
    int aK0 = wm * 16384 + l16 * 128 + swz;
    int aK1 = aK0 ^ 64;
    int bK0 = 32768 + wn * 8192 + l16 * 128 + swz;
    int bK1 = bK0 ^ 64;

    const char* xtB = (const char*)xt;
    auto SA = [&](char* buf, const char* srcTile, int roff) {
        gl_lds16(srcTile + adst0 + roff + lane16, buf + adst0 + roff);
        gl_lds16(srcTile + adst1 + roff + lane16, buf + adst1 + roff);
    };
    // bo(ks) [bytes] = tapShift(ks)*512 + cb(ks)*64
    auto SB = [&](char* buf, int bo0, int bo1, int h) {
        int bsel = (ksl ? bo1 : bo0) + c2off;
        gl_lds16(xtB + (size_t)(unsigned)(bsel + (h ? pix01 : pix00)),
                 buf + 32768 + bdst0 + h * 4096);
        gl_lds16(xtB + (size_t)(unsigned)(bsel + (h ? pix11 : pix10)),
                 buf + 32768 + bdst1 + h * 4096);
    };
    auto BO = [&](int ks) {
        int cb = ks / 9, tap = ks - cb * 9;
        return ((tap / 3) * 58 + (tap - (tap / 3) * 3)) * 512 + cb * 64;
    };

    f32x4 acc[8][4] = {};
    s8v aE0[4], aE1[4], aO0[4], aO1[4];
    s8v bE0[2], bE1[2], bO0[2], bO1[2];

    #define MFMA_Q(MH, NH, A0, A1, B0, B1)                                         \
        __builtin_amdgcn_s_setprio(1);                                             \
        _Pragma("unroll")                                                          \
        for (int f = 0; f < 4; ++f) {                                              \
            _Pragma("unroll")                                                      \
            for (int g = 0; g < 2; ++g)                                            \
                acc[(MH)*4+f][(NH)*2+g] = __builtin_amdgcn_mfma_f32_16x16x32_bf16( \
                    A0[f], B0[g], acc[(MH)*4+f][(NH)*2+g], 0, 0, 0);               \
        }                                                                          \
        _Pragma("unroll")                                                          \
        for (int f = 0; f < 4; ++f) {                                              \
            _Pragma("unroll")                                                      \
            for (int g = 0; g < 2; ++g)                                            \
                acc[(MH)*4+f][(NH)*2+g] = __builtin_amdgcn_mfma_f32_16x16x32_bf16( \
                    A1[f], B1[g], acc[(MH)*4+f][(NH)*2+g], 0, 0, 0);               \
        }                                                                          \
        __builtin_amdgcn_s_setprio(0);

    // ---- prologue: tile0 full; tile1 {A-mh0, B-nh0, B-nh1}
    SA(lds, (const char*)wt, 0);
    SA(lds, (const char*)wt, 8192);
    SB(lds, BO(0), BO(1), 0);
    SB(lds, BO(0), BO(1), 1);
    SA(lds + 65536, (const char*)wt + 32768, 0);
    SB(lds + 65536, BO(2), BO(3), 0);
    SB(lds + 65536, BO(2), BO(3), 1);
    asm volatile("s_waitcnt vmcnt(6)" ::: "memory");
    BAR();
    // pre-read aE(0), bE(0)
    #pragma unroll
    for (int f = 0; f < 4; ++f) {
        aE0[f] = *(const s8v*)(lds + aK0 + f * 2048);
        aE1[f] = *(const s8v*)(lds + aK1 + f * 2048);
    }
    #pragma unroll
    for (int g = 0; g < 2; ++g) {
        bE0[g] = *(const s8v*)(lds + bK0 + g * 2048);
        bE1[g] = *(const s8v*)(lds + bK1 + g * 2048);
    }

    #pragma unroll 1
    for (int t = 0; t < 36; ++t) {
        char* bufc = lds + (t & 1) * 65536;
        char* bufo = lds + ((t & 1) ^ 1) * 65536;
        const char* wA1 = (const char*)wt + (size_t)(t + 1) * 32768;
        const char* wA0 = (const char*)wt + (size_t)(t + 2) * 32768;
        int kk  = 2 * (t + 2);
        int bo0 = BO(kk);
        int bo1 = BO(kk + 1);

        // ---- P0: read bO(t); stage (t+1,A-mh1); MFMA q00 (aE,bE)
        BAR();
        #pragma unroll
        for (int g = 0; g < 2; ++g) {
            bO0[g] = *(const s8v*)(bufc + bK0 + 4096 + g * 2048);
            bO1[g] = *(const s8v*)(bufc + bK1 + 4096 + g * 2048);
        }
        if (t < 35) SA(bufo, wA1, 8192);
        MFMA_Q(0, 0, aE0, aE1, bE0, bE1)
        GATE(t);

        // ---- P1: read aO-ks0(t); stage (t+2,A-mh0); MFMA q01 (aE,bO)
        BAR();
        #pragma unroll
        for (int f = 0; f < 4; ++f)
            aO0[f] = *(const s8v*)(bufc + aK0 + 8192 + f * 2048);
        if (t < 34) SA(bufc, wA0, 0);
        MFMA_Q(0, 1, aE0, aE1, bO0, bO1)
        GATE(t);

        // ---- P2: read aO-ks1(t) + aE-ks0(t+1); stage (t+2,B-nh0); MFMA q10 (aO,bE)
        BAR();
        #pragma unroll
        for (int f = 0; f < 4; ++f)
            aO1[f] = *(const s8v*)(bufc + aK1 + 8192 + f * 2048);
        if (t < 35) {
            #pragma unroll
            for (int f = 0; f < 4; ++f)
                aE0[f] = *(const s8v*)(bufo + aK0 + f * 2048);
        }
        if (t < 34) SB(bufc, bo0, bo1, 0);
        MFMA_Q(1, 0, aO0, aO1, bE0, bE1)
        GATE(t);

        // ---- P3: read aE-ks1(t+1) + bE(t+1); stage (t+2,B-nh1); MFMA q11 (aO,bO)
        BAR();
        if (t < 35) {
            #pragma unroll
            for (int f = 0; f < 4; ++f)
                aE1[f] = *(const s8v*)(bufo + aK1 + f * 2048);
            #pragma unroll
            for (int g = 0; g < 2; ++g) {
                bE0[g] = *(const s8v*)(bufo + bK0 + g * 2048);
                bE1[g] = *(const s8v*)(bufo + bK1 + g * 2048);
            }
        }
        if (t < 34) SB(bufc, bo0, bo1, 1);
        MFMA_Q(1, 1, aO0, aO1, bO0, bO1)
        GATE(t);
    }

    // Epilogue: C/D layout col=l16 (n), row=quad*4+reg (m=o). out is [O][N_TOT].
    float* op = out + (size_t)(wm * 128 + quad * 4) * N_TOT + nt * 256 + wn * 64 + l16;
    #pragma unroll
    for (int f = 0; f < 8; ++f)
        #pragma unroll
        for (int rr = 0; rr < 4; ++rr) {
            float* orow = op + (size_t)(f * 16 + rr) * N_TOT;
            #pragma unroll
            for (int g = 0; g < 4; ++g)
                orow[g * 16] = acc[f][g][rr];
        }
}

// Fallback if workspace too small: direct conv, one thread per output.
__global__ void conv_naive(const float* __restrict__ x, const float* __restrict__ wq,
                           float* __restrict__ out) {
    int f = blockIdx.x * 256 + threadIdx.x;
    int o = f / N_TOT;
    int n = f - o * N_TOT;
    int b = n / 3136; int r = n - b * 3136; int h = r / 56; int w = r - h * 56;
    const float* xb = x + (size_t)b * 256 * 3136;
    const float* wo = wq + o * 2304;
    float acc = 0.f;
    for (int c = 0; c < 256; ++c) {
        const float* xc = xb + c * 3136;
        const float* wc = wo + c * 9;
        #pragma unroll
        for (int dh = 0; dh < 3; ++dh) {
            int ih = h + dh - 1;
            if (ih < 0 || ih >= 56) continue;
            const float* xr = xc + ih * 56;
            #pragma unroll
            for (int dw = 0; dw < 3; ++dw) {
                int iw = w + dw - 1;
                if (iw >= 0 && iw < 56) acc += xr[iw] * wc[dh * 3 + dw];
            }
        }
    }
    out[f] = acc;
}

extern "C" void kernel_launch(void* const* d_in, const int* in_sizes, int n_in,
                              void* d_out, int out_size, void* d_ws, size_t ws_size,
                              hipStream_t stream) {
    const float* x = (const float*)d_in[0];
    const float* w = (const float*)d_in[1];
    float* out = (float*)d_out;
    if (ws_size >= (size_t)WS_NEED) {
        unsigned short* wt = (unsigned short*)d_ws;
        unsigned short* xt = wt + WT_ELEMS;
        static int attr_done = 0;
        if (!attr_done) {
            hipFuncSetAttribute((const void*)gemm8,
                                hipFuncAttributeMaxDynamicSharedMemorySize, 131072);
            attr_done = 1;
        }
        prep_w<<<288, 256, 0, stream>>>(w, wt);
        prep_x<<<32 * 58, 256, 0, stream>>>(x, xt);
        gemm8<<<392, 512, 131072, stream>>>(wt, xt, out);
    } else {
        conv_naive<<<N_TOT, 256, 0, stream>>>(x, w, out);
    }
}